// Round 1
// baseline (1077.014 us; speedup 1.0000x reference)
//
#include <hip/hip_runtime.h>
#include <math.h>

// Problem dims
#define TB 16   // batch (tasks)
#define TT 16   // train steps
#define LL 128  // test length
#define XX 256  // x dim
#define HH 512  // hidden
#define YY 256  // y dim

__device__ __forceinline__ float wred(float v) {
    v += __shfl_xor(v, 32);
    v += __shfl_xor(v, 16);
    v += __shfl_xor(v, 8);
    v += __shfl_xor(v, 4);
    v += __shfl_xor(v, 2);
    v += __shfl_xor(v, 1);
    return v;
}

// ---------------------------------------------------------------------------
// Precompute: Z1base[b][t] = W1@x_t + b1 ; G1[b][s][t] = x_s.x_t + 1 ;
// H1[b][0] = relu(Z1base[b][0]) ; out[2048] = exp(loglr)
// grid: B*T blocks of 256
// ---------------------------------------------------------------------------
__global__ __launch_bounds__(256) void k_pre(
    const float* __restrict__ tx, const float* __restrict__ W1,
    const float* __restrict__ b1, const float* __restrict__ loglr,
    float* __restrict__ Z1base, float* __restrict__ G1,
    float* __restrict__ H1, float* __restrict__ out)
{
    const int blk = blockIdx.x;
    const int b = blk / TT, t = blk % TT;
    const int tid = threadIdx.x, lane = tid & 63, w = tid >> 6;

    __shared__ float sx[XX];
    sx[tid] = tx[(b * TT + t) * XX + tid];
    __syncthreads();

    if (b == 0 && t == 0 && tid == 0) out[2048] = expf(loglr[0]);

    if (w == 0) {
        for (int s = 0; s < TT; ++s) {
            const float4 xv = *(const float4*)&tx[(b * TT + s) * XX + lane * 4];
            float a = xv.x * sx[lane * 4] + xv.y * sx[lane * 4 + 1] +
                      xv.z * sx[lane * 4 + 2] + xv.w * sx[lane * 4 + 3];
            a = wred(a);
            if (lane == 0) G1[(b * TT + s) * TT + t] = a + 1.0f;
        }
    }

    float xr0, xr1, xr2, xr3;
    { const float4 xv = *(const float4*)&sx[lane * 4];
      xr0 = xv.x; xr1 = xv.y; xr2 = xv.z; xr3 = xv.w; }
    for (int r = 0; r < 128; ++r) {
        const int row = w * 128 + r;
        const float4 wv = *(const float4*)&W1[row * XX + lane * 4];
        float a = wv.x * xr0 + wv.y * xr1 + wv.z * xr2 + wv.w * xr3;
        a = wred(a);
        if (lane == 0) {
            const float z = a + b1[row];
            Z1base[(b * TT + t) * HH + row] = z;
            if (t == 0) H1[(b * TT + 0) * HH + row] = fmaxf(z, 0.0f);
        }
    }
}

// ---------------------------------------------------------------------------
// Forward low-rank matvec stage (F2 / F3 / F4).
// out[row] = post( W[row,:].in + bias - lr*sum_{s<t} D[b][s][row]*c[s] )
// c[s] = hist[b][s].in (+1), in = hist[b][t].
// grid: B*(OUT/64) blocks of 256
// ---------------------------------------------------------------------------
template <int OUT, bool RELU, bool GATE, bool PLUSONE, bool BIAS>
__global__ __launch_bounds__(256) void k_fwd(
    const float* __restrict__ W, const float* __restrict__ bias,
    const float* __restrict__ hist, const float* __restrict__ Darr,
    const float* __restrict__ gateb, float* __restrict__ outb,
    long out_bstride, const float* __restrict__ loglr, int t)
{
    constexpr int RC = OUT / 64;
    const int b = blockIdx.x / RC, rc = blockIdx.x % RC;
    const int tid = threadIdx.x, lane = tid & 63, w = tid >> 6;
    const float lr = expf(loglr[0]);

    __shared__ float s_in[HH];
    __shared__ float s_c[TT];
    __shared__ float s_corr[64];

    s_in[tid]       = hist[(b * TT + t) * HH + tid];
    s_in[tid + 256] = hist[(b * TT + t) * HH + tid + 256];
    __syncthreads();

    for (int s = w; s < t; s += 4) {
        const float4 h0 = *(const float4*)&hist[(b * TT + s) * HH + lane * 8];
        const float4 h1 = *(const float4*)&hist[(b * TT + s) * HH + lane * 8 + 4];
        float a = h0.x * s_in[lane * 8]     + h0.y * s_in[lane * 8 + 1] +
                  h0.z * s_in[lane * 8 + 2] + h0.w * s_in[lane * 8 + 3] +
                  h1.x * s_in[lane * 8 + 4] + h1.y * s_in[lane * 8 + 5] +
                  h1.z * s_in[lane * 8 + 6] + h1.w * s_in[lane * 8 + 7];
        a = wred(a);
        if (lane == 0) s_c[s] = a + (PLUSONE ? 1.0f : 0.0f);
    }
    __syncthreads();

    if (tid < 64) {
        const int row = rc * 64 + tid;
        float cr = 0.0f;
        for (int s = 0; s < t; ++s) cr += Darr[(b * TT + s) * OUT + row] * s_c[s];
        s_corr[tid] = lr * cr;
    }
    __syncthreads();

    float xr[8];
    {
        const float4 a0 = *(const float4*)&s_in[lane * 8];
        const float4 a1 = *(const float4*)&s_in[lane * 8 + 4];
        xr[0] = a0.x; xr[1] = a0.y; xr[2] = a0.z; xr[3] = a0.w;
        xr[4] = a1.x; xr[5] = a1.y; xr[6] = a1.z; xr[7] = a1.w;
    }
    for (int r = 0; r < 16; ++r) {
        const int row = rc * 64 + w * 16 + r;
        const float4 w0 = *(const float4*)&W[row * HH + lane * 8];
        const float4 w1 = *(const float4*)&W[row * HH + lane * 8 + 4];
        float a = w0.x * xr[0] + w0.y * xr[1] + w0.z * xr[2] + w0.w * xr[3] +
                  w1.x * xr[4] + w1.y * xr[5] + w1.z * xr[6] + w1.w * xr[7];
        a = wred(a);
        if (lane == 0) {
            float v = a - s_corr[w * 16 + r];
            if constexpr (BIAS) v += bias[row];
            if constexpr (RELU) v = fmaxf(v, 0.0f);
            if constexpr (GATE) v *= gateb[(long)b * TT * HH + row];
            outb[(long)b * out_bstride + row] = v;
        }
    }
}

// ---------------------------------------------------------------------------
// Backward layer-4: dlogit from LOGIT/train_y; write D4[b][t]; then
// dz3[h] = (W4^T dlg - lr*sum_s HG[b][s][h]*bc[s]) * gate * (HG[b][t][h]>0)
// grid: B*8 blocks of 256
// ---------------------------------------------------------------------------
__global__ __launch_bounds__(256) void k_bwd4(
    const float* __restrict__ W4, const float* __restrict__ ty,
    const float* __restrict__ tg, const float* __restrict__ LOG,
    const float* __restrict__ HG, float* __restrict__ D4,
    float* __restrict__ D3, const float* __restrict__ loglr, int t)
{
    const int b = blockIdx.x >> 3, hc = blockIdx.x & 7;
    const int tid = threadIdx.x, lane = tid & 63, w = tid >> 6;
    const float lr = expf(loglr[0]);

    __shared__ float s_dlg[YY];
    __shared__ float s_bc[TT];
    __shared__ float s_part[4][64];

    s_dlg[tid] = (LOG[b * YY + tid] - ty[(b * TT + t) * YY + tid]) * (2.0f / YY);
    __syncthreads();
    if (hc == 0) D4[(b * TT + t) * YY + tid] = s_dlg[tid];

    for (int s = w; s < t; s += 4) {
        const float4 d0 = *(const float4*)&D4[(b * TT + s) * YY + lane * 4];
        float a = d0.x * s_dlg[lane * 4]     + d0.y * s_dlg[lane * 4 + 1] +
                  d0.z * s_dlg[lane * 4 + 2] + d0.w * s_dlg[lane * 4 + 3];
        a = wred(a);
        if (lane == 0) s_bc[s] = lr * a;
    }
    __syncthreads();

    const int h = hc * 64 + lane;
    float acc = 0.0f;
    for (int y = w * 64; y < w * 64 + 64; ++y) acc += W4[y * HH + h] * s_dlg[y];
    s_part[w][lane] = acc;
    __syncthreads();

    if (tid < 64) {
        const int hh = hc * 64 + tid;
        float sum = s_part[0][tid] + s_part[1][tid] + s_part[2][tid] + s_part[3][tid];
        for (int s = 0; s < t; ++s) sum -= HG[(b * TT + s) * HH + hh] * s_bc[s];
        const float g = tg[(b * TT + t) * HH + hh];
        const float m = (HG[(b * TT + t) * HH + hh] > 0.0f) ? 1.0f : 0.0f;
        D3[(b * TT + t) * HH + hh] = sum * g * m;
    }
}

// ---------------------------------------------------------------------------
// Backward layers 3 and 2 (EPI=true also produces next step's h1).
// dz_out[j] = (W^T dz_in - lr*sum_s hist[b][s][j]*bc[s]) * (hist[b][t][j]>0)
// grid: B*8 blocks of 256
// ---------------------------------------------------------------------------
template <bool EPI>
__global__ __launch_bounds__(256) void k_bwd(
    const float* __restrict__ W, const float* __restrict__ Din,
    const float* __restrict__ hist, float* __restrict__ Dout,
    const float* __restrict__ Z1base, const float* __restrict__ G1,
    float* __restrict__ H1, const float* __restrict__ loglr, int t)
{
    const int b = blockIdx.x >> 3, hc = blockIdx.x & 7;
    const int tid = threadIdx.x, lane = tid & 63, w = tid >> 6;
    const float lr = expf(loglr[0]);

    __shared__ float s_v[HH];
    __shared__ float s_bc[TT];
    __shared__ float s_part[4][64];
    __shared__ float s_g[TT];

    s_v[tid]       = Din[(b * TT + t) * HH + tid];
    s_v[tid + 256] = Din[(b * TT + t) * HH + tid + 256];
    __syncthreads();

    for (int s = w; s < t; s += 4) {
        const float4 d0 = *(const float4*)&Din[(b * TT + s) * HH + lane * 8];
        const float4 d1 = *(const float4*)&Din[(b * TT + s) * HH + lane * 8 + 4];
        float a = d0.x * s_v[lane * 8]     + d0.y * s_v[lane * 8 + 1] +
                  d0.z * s_v[lane * 8 + 2] + d0.w * s_v[lane * 8 + 3] +
                  d1.x * s_v[lane * 8 + 4] + d1.y * s_v[lane * 8 + 5] +
                  d1.z * s_v[lane * 8 + 6] + d1.w * s_v[lane * 8 + 7];
        a = wred(a);
        if (lane == 0) s_bc[s] = lr * a;
    }
    if (EPI && tid < TT)
        s_g[tid] = G1[(b * TT + tid) * TT + ((t + 1 < TT) ? (t + 1) : 0)];
    __syncthreads();

    const int h = hc * 64 + lane;
    float acc = 0.0f;
    for (int i = w * 128; i < w * 128 + 128; ++i) acc += W[i * HH + h] * s_v[i];
    s_part[w][lane] = acc;
    __syncthreads();

    if (tid < 64) {
        const int hh = hc * 64 + tid;
        float sum = s_part[0][tid] + s_part[1][tid] + s_part[2][tid] + s_part[3][tid];
        for (int s = 0; s < t; ++s) sum -= hist[(b * TT + s) * HH + hh] * s_bc[s];
        const float m = (hist[(b * TT + t) * HH + hh] > 0.0f) ? 1.0f : 0.0f;
        const float dz = sum * m;
        Dout[(b * TT + t) * HH + hh] = dz;
        if (EPI && (t + 1 < TT)) {
            float cr = dz * s_g[t];
            for (int s = 0; s < t; ++s) cr += Dout[(b * TT + s) * HH + hh] * s_g[s];
            const float z = Z1base[(b * TT + t + 1) * HH + hh];
            H1[(b * TT + (t + 1)) * HH + hh] = fmaxf(z - lr * cr, 0.0f);
        }
    }
}

// ---------------------------------------------------------------------------
// Phase-2 inner products: ip[b][s][l] = A[b][s] . (act[b][l] *? tg[b][l]) (+1)
// grid: B*T blocks of 256
// ---------------------------------------------------------------------------
template <int K, bool PLUSONE, bool GATE>
__global__ __launch_bounds__(256) void k_ip(
    const float* __restrict__ A, const float* __restrict__ act,
    const float* __restrict__ tg, float* __restrict__ ip)
{
    const int b = blockIdx.x / TT, s = blockIdx.x % TT;
    const int tid = threadIdx.x, lane = tid & 63, w = tid >> 6;
    constexpr int E = K / 64;

    float ar[E];
    #pragma unroll
    for (int j = 0; j < E; j += 4) {
        const float4 v = *(const float4*)&A[(b * TT + s) * K + lane * E + j];
        ar[j] = v.x; ar[j + 1] = v.y; ar[j + 2] = v.z; ar[j + 3] = v.w;
    }
    for (int l0 = 0; l0 < 32; ++l0) {
        const int l = w * 32 + l0;
        float a = 0.0f;
        #pragma unroll
        for (int j = 0; j < E; j += 4) {
            const float4 v = *(const float4*)&act[((long)b * LL + l) * K + lane * E + j];
            float gx = 1.0f, gy = 1.0f, gz = 1.0f, gw = 1.0f;
            if constexpr (GATE) {
                const float4 g = *(const float4*)&tg[((long)b * LL + l) * K + lane * E + j];
                gx = g.x; gy = g.y; gz = g.z; gw = g.w;
            }
            a += v.x * gx * ar[j] + v.y * gy * ar[j + 1] +
                 v.z * gz * ar[j + 2] + v.w * gw * ar[j + 3];
        }
        a = wred(a);
        if (lane == 0) ip[(b * TT + s) * LL + l] = a + (PLUSONE ? 1.0f : 0.0f);
    }
}

// ---------------------------------------------------------------------------
// Phase-2 layer: out[b][l][n] = post( W@act + bias - lr*sum_s D[s][n]*ip[s][l] )
// tile: 64 n x 32 l per WG; thread computes 2n x 4l.
// grid: B*(OUT/64)*(L/32) blocks of 256
// ---------------------------------------------------------------------------
template <int K, int OUT, bool RELU, bool BIAS, bool GATEIN>
__global__ __launch_bounds__(256) void k_layer(
    const float* __restrict__ W, const float* __restrict__ bias,
    const float* __restrict__ act, const float* __restrict__ tg,
    const float* __restrict__ Dl, const float* __restrict__ ip,
    float* __restrict__ outp, const float* __restrict__ loglr)
{
    constexpr int NC = OUT / 64;
    const int blk = blockIdx.x;
    const int b = blk / (NC * 4);
    const int rem = blk % (NC * 4);
    const int nc = rem / 4, lc = rem % 4;
    const int base_n = nc * 64, base_l = lc * 32;
    const int tid = threadIdx.x;
    const int tn = tid & 31, tl = tid >> 5;  // tl in 0..7
    const float lr = expf(loglr[0]);

    __shared__ float lw[64][65];
    __shared__ float lx[32][65];
    __shared__ float sD[TT][64];
    __shared__ float sip[TT][32];

    #pragma unroll
    for (int rep = 0; rep < 4; ++rep) {
        const int flat = rep * 256 + tid;
        const int s = flat >> 6, n = flat & 63;
        sD[s][n] = Dl[(b * TT + s) * OUT + base_n + n];
    }
    #pragma unroll
    for (int rep = 0; rep < 2; ++rep) {
        const int flat = rep * 256 + tid;
        const int s = flat >> 5, l = flat & 31;
        sip[s][l] = ip[(b * TT + s) * LL + base_l + l];
    }

    float acc[2][4] = {};
    for (int kc = 0; kc < K; kc += 64) {
        __syncthreads();
        #pragma unroll
        for (int rep = 0; rep < 16; ++rep) {
            const int flat = rep * 256 + tid;
            const int i = flat >> 6, k = flat & 63;
            lw[i][k] = W[(base_n + i) * K + kc + k];
        }
        #pragma unroll
        for (int rep = 0; rep < 8; ++rep) {
            const int flat = rep * 256 + tid;
            const int l = flat >> 6, k = flat & 63;
            float v = act[((long)b * LL + base_l + l) * K + kc + k];
            if constexpr (GATEIN)
                v *= tg[((long)b * LL + base_l + l) * K + kc + k];
            lx[l][k] = v;
        }
        __syncthreads();
        #pragma unroll 4
        for (int k = 0; k < 64; ++k) {
            const float w0 = lw[tn][k], w1 = lw[tn + 32][k];
            const float x0 = lx[tl][k],      x1 = lx[tl + 8][k];
            const float x2 = lx[tl + 16][k], x3 = lx[tl + 24][k];
            acc[0][0] += w0 * x0; acc[0][1] += w0 * x1;
            acc[0][2] += w0 * x2; acc[0][3] += w0 * x3;
            acc[1][0] += w1 * x0; acc[1][1] += w1 * x1;
            acc[1][2] += w1 * x2; acc[1][3] += w1 * x3;
        }
    }

    #pragma unroll
    for (int i = 0; i < 2; ++i) {
        const int n = base_n + tn + i * 32;
        const float bv = BIAS ? bias[n] : 0.0f;
        #pragma unroll
        for (int j = 0; j < 4; ++j) {
            const int l = base_l + tl + j * 8;
            float corr = 0.0f;
            #pragma unroll
            for (int s = 0; s < TT; ++s)
                corr += sD[s][tn + i * 32] * sip[s][tl + j * 8];
            float v = acc[i][j] + bv - lr * corr;
            if constexpr (RELU) v = fmaxf(v, 0.0f);
            outp[((long)b * LL + l) * OUT + n] = v;
        }
    }
}

// ---------------------------------------------------------------------------
// Loss: per (b,l): mean_y (logit-ty)^2 -> loss and evaluation
// grid: B*L blocks of 64
// ---------------------------------------------------------------------------
__global__ __launch_bounds__(64) void k_loss(
    const float* __restrict__ logit, const float* __restrict__ tey,
    float* __restrict__ loss, float* __restrict__ evalo)
{
    const int idx = blockIdx.x;
    const int lane = threadIdx.x;
    float a = 0.0f;
    #pragma unroll
    for (int j = 0; j < 4; ++j) {
        const float d = logit[(long)idx * YY + lane * 4 + j] -
                        tey[(long)idx * YY + lane * 4 + j];
        a += d * d;
    }
    a = wred(a);
    if (lane == 0) {
        const float v = a * (1.0f / YY);
        loss[idx] = v;
        evalo[idx] = v;
    }
}

// ---------------------------------------------------------------------------
extern "C" void kernel_launch(void* const* d_in, const int* in_sizes, int n_in,
                              void* d_out, int out_size, void* d_ws, size_t ws_size,
                              hipStream_t stream)
{
    const float* tx    = (const float*)d_in[0];   // train_x  [B][T][X]
    const float* ty    = (const float*)d_in[1];   // train_y  [B][T][Y]
    const float* tex   = (const float*)d_in[2];   // test_x   [B][L][X]
    const float* tey   = (const float*)d_in[3];   // test_y   [B][L][Y]
    const float* tg    = (const float*)d_in[4];   // train_gate [B][T][H]
    const float* teg   = (const float*)d_in[5];   // test_gate  [B][L][H]
    const float* W1    = (const float*)d_in[6];
    const float* b1    = (const float*)d_in[7];
    const float* W2    = (const float*)d_in[8];
    const float* b2    = (const float*)d_in[9];
    const float* W3    = (const float*)d_in[10];
    const float* b3    = (const float*)d_in[11];
    const float* W4    = (const float*)d_in[12];
    const float* loglr = (const float*)d_in[13];

    float* out = (float*)d_out;
    float* ws  = (float*)d_ws;

    // workspace layout (floats)
    float* Z1base = ws;                 // 131072
    float* G1     = ws + 131072;        // 4096
    float* H1     = ws + 135168;        // 131072
    float* H2     = ws + 266240;        // 131072
    float* HG     = ws + 397312;        // 131072
    float* D1     = ws + 528384;        // 131072
    float* D2     = ws + 659456;        // 131072
    float* D3     = ws + 790528;        // 131072
    float* D4     = ws + 921600;        // 65536
    float* LOG    = ws + 987136;        // 4096
    float* IP     = ws + 991232;        // 32768
    float* ActA   = ws + 1024000;       // 1048576
    float* ActB   = ws + 2072576;       // 1048576
    // total 3,121,152 floats = ~12.5 MB

    k_pre<<<TB * TT, 256, 0, stream>>>(tx, W1, b1, loglr, Z1base, G1, H1, out);

    for (int t = 0; t < TT; ++t) {
        // F2: z2 = W2@h1 + b2 - lr*sum D2[s]*(h1_s.h1_t+1) ; h2 = relu
        k_fwd<HH, true, false, true, true><<<TB * 8, 256, 0, stream>>>(
            W2, b2, H1, D2, nullptr, H2 + t * HH, (long)TT * HH, loglr, t);
        // F3: h3 = relu(z3); store HG = h3*gate_t
        k_fwd<HH, true, true, true, true><<<TB * 8, 256, 0, stream>>>(
            W3, b3, H2, D3, tg + (long)t * HH, HG + t * HH, (long)TT * HH, loglr, t);
        // F4: logit = W4@hg - lr*sum D4[s]*(hg_s.hg_t)
        k_fwd<YY, false, false, false, false><<<TB * 4, 256, 0, stream>>>(
            W4, nullptr, HG, D4, nullptr, LOG, (long)YY, loglr, t);
        // B4 -> D3[b][t]
        k_bwd4<<<TB * 8, 256, 0, stream>>>(W4, ty, tg, LOG, HG, D4, D3, loglr, t);
        // B3 -> D2[b][t]
        k_bwd<false><<<TB * 8, 256, 0, stream>>>(
            W3, D3, H2, D2, nullptr, nullptr, nullptr, loglr, t);
        // B2 -> D1[b][t], plus h1_{t+1}
        k_bwd<true><<<TB * 8, 256, 0, stream>>>(
            W2, D2, H1, D1, Z1base, G1, H1, loglr, t);
    }

    // ---- Phase 2: test-set forward with final (rank-16-corrected) weights ----
    k_ip<XX, true, false><<<TB * TT, 256, 0, stream>>>(tx, tex, nullptr, IP);
    k_layer<XX, HH, true, true, false><<<TB * 8 * 4, 256, 0, stream>>>(
        W1, b1, tex, nullptr, D1, IP, ActA, loglr);

    k_ip<HH, true, false><<<TB * TT, 256, 0, stream>>>(H1, ActA, nullptr, IP);
    k_layer<HH, HH, true, true, false><<<TB * 8 * 4, 256, 0, stream>>>(
        W2, b2, ActA, nullptr, D2, IP, ActB, loglr);

    k_ip<HH, true, false><<<TB * TT, 256, 0, stream>>>(H2, ActB, nullptr, IP);
    k_layer<HH, HH, true, true, false><<<TB * 8 * 4, 256, 0, stream>>>(
        W3, b3, ActB, nullptr, D3, IP, ActA, loglr);

    k_ip<HH, false, true><<<TB * TT, 256, 0, stream>>>(HG, ActA, teg, IP);
    k_layer<HH, YY, false, false, true><<<TB * 4 * 4, 256, 0, stream>>>(
        W4, nullptr, ActA, teg, D4, IP, out + 4097, loglr);

    k_loss<<<TB * LL, 64, 0, stream>>>(out + 4097, tey, out, out + 2049);
}